// Round 5
// baseline (230.084 us; speedup 1.0000x reference)
//
#include <hip/hip_runtime.h>
#include <hip/hip_bf16.h>

#define B_  256
#define H_  1024
#define D_  256
#define G_  32
#define C_  16
#define O_  256
#define HD_ 1280          // H + D
#define N1_ 16384         // C*H

typedef __attribute__((ext_vector_type(8)))  short short8;
typedef __attribute__((ext_vector_type(4)))  short s16x4;
typedef __attribute__((ext_vector_type(4)))  float f32x4;
typedef __attribute__((ext_vector_type(16))) float f32x16;

#define MFMA32(a, b, c) __builtin_amdgcn_mfma_f32_32x32x16_bf16((a), (b), (c), 0, 0, 0)

// tanh via fast exp + hw rcp; clamped to +-(1-6e-8) so that the downstream
// blend denominator 1 + tA*tB is always > 0 (never 0*inf = NaN).
__device__ __forceinline__ float tanh_c(float x) {
    float y = __expf(2.f * x);
    float t = 1.f - 2.f * __builtin_amdgcn_rcpf(y + 1.f);
    return fminf(fmaxf(t, -0.99999994f), 0.99999994f);
}

// Split fp32 into bf16 hi + bf16 lo (both truncated).
__device__ __forceinline__ short bfhi(float x) {
    return (short)(__float_as_uint(x) >> 16);
}
__device__ __forceinline__ short bflo(float x) {
    float fhi = __uint_as_float(__float_as_uint(x) & 0xFFFF0000u);
    return (short)(__float_as_uint(x - fhi) >> 16);
}

__device__ __forceinline__ void split4(const float4 v, s16x4& hi, s16x4& lo) {
    hi[0] = bfhi(v.x); lo[0] = bflo(v.x);
    hi[1] = bfhi(v.y); lo[1] = bflo(v.y);
    hi[2] = bfhi(v.z); lo[2] = bflo(v.z);
    hi[3] = bfhi(v.w); lo[3] = bflo(v.w);
}

// ---------------------------------------------------------------------------
// Kernel 1: tA[b, c*H+o] = tanh( sum_h hidden[b,h]*attn_w[c,o,h] + attn_b[c,o] )
// GEMM M=256, N=16384, K=1024.  Round-5 structure: ZERO LDS, ZERO barriers.
//   - A: prepacked MFMA fragments (bf16 hi/lo planes, fragment order, from
//     gemm2's prepass) -> coalesced 16B/lane loads from the L2-resident 1MB
//     buffer.  BM=128 (vs 256) halves A L2 re-read traffic to 256MB.
//   - B: fragment loaded DIRECTLY from attn_w (lane l31 reads row n0+wn+l31,
//     two dwordx4 per k-half; the pair sits in one 64B line, and successive
//     slabs consume the rest of the line) and split to bf16 hi/lo in-register.
//   - 3-deep register pipeline (sets indexed mod 3, all literals): compute
//     slab K from set K%3, then refill that set with slab K+3 => ~2 bodies
//     (~300+ cy) of latency cover.  Waves fully independent; round-4's
//     per-slab barrier+lgkmcnt drain (the 3x overhead) is gone.
// Tile: BM=128 x BN=64, grid (2,256), 4 waves = 2m x 2n, wave = 64m x 32n.
// ---------------------------------------------------------------------------
__global__ __launch_bounds__(256, 2) void gemm1_kernel(
    const short* __restrict__ hidH, const short* __restrict__ hidL,
    const float* __restrict__ attn_w, const float* __restrict__ attn_b,
    float* __restrict__ hp)
{
    const int tid  = threadIdx.x;
    const int wave = tid >> 6, lane = tid & 63;
    const int l31 = lane & 31;
    const int kh  = (lane >> 5) * 8;          // k-half lane offset (elems)

    const int n0 = blockIdx.y * 64 + (wave & 1) * 32;     // this wave's n
    const int s0 = blockIdx.x * 4 + (wave >> 1) * 2;      // m-strips s0, s0+1

    f32x16 acc0, acc1;
    #pragma unroll
    for (int i = 0; i < 16; ++i) { acc0[i] = 0.f; acc1[i] = 0.f; }

    // A fragment bases (hidP layout: [s][k0][ks][lane][8] shorts)
    const size_t aBase = (size_t)s0 * 32768 + (size_t)lane * 8;
    const short* pH0 = hidH + aBase;
    const short* pH1 = hidH + aBase + 32768;
    const short* pL0 = hidL + aBase;
    const short* pL1 = hidL + aBase + 32768;

    // B fragment base: lane l31 owns row n0+l31; k = k0*32 + ks*16 + kh + j
    const float* pBr = attn_w + (size_t)(n0 + l31) * HD_ + kh;

    // 3-deep register sets (all indices compile-time literals)
    short8 aH0[3][2], aH1[3][2], aL0[3][2], aL1[3][2];   // [set][ks]
    float4 rb[3][4];                                     // [set][ks*2 + half]

#define LOADA(SET, KS)                                                        \
    {                                                                         \
        const int o_ = (KS) * 1024;                                           \
        aH0[SET][0] = *(const short8*)(pH0 + o_);                             \
        aH0[SET][1] = *(const short8*)(pH0 + o_ + 512);                       \
        aH1[SET][0] = *(const short8*)(pH1 + o_);                             \
        aH1[SET][1] = *(const short8*)(pH1 + o_ + 512);                       \
        aL0[SET][0] = *(const short8*)(pL0 + o_);                             \
        aL0[SET][1] = *(const short8*)(pL0 + o_ + 512);                       \
        aL1[SET][0] = *(const short8*)(pL1 + o_);                             \
        aL1[SET][1] = *(const short8*)(pL1 + o_ + 512);                       \
    }
#define LOADB(SET, KS)                                                        \
    {                                                                         \
        const float* p_ = pBr + (KS) * 32;                                    \
        rb[SET][0] = *(const float4*)(p_);                                    \
        rb[SET][1] = *(const float4*)(p_ + 4);                                \
        rb[SET][2] = *(const float4*)(p_ + 16);                               \
        rb[SET][3] = *(const float4*)(p_ + 20);                               \
    }

    // prologue: slabs 0,1,2 -> sets 0,1,2
    LOADB(0, 0) LOADA(0, 0)
    LOADB(1, 1) LOADA(1, 1)
    LOADB(2, 2) LOADA(2, 2)

    // BODY(P, K, DOL): compute slab K from set P; refill set P with slab K+3.
    // B of set P is consumed into bh/bl temps before the refill, so LOADB can
    // issue ahead of the MFMA cluster; LOADA must follow it (operands live).
#define BODY(P, K, DOL)                                                       \
    {                                                                         \
        short8 bh0, bl0, bh1, bl1;                                            \
        {                                                                     \
            s16x4 h0, l0, h1, l1;                                             \
            split4(rb[P][0], h0, l0); split4(rb[P][1], h1, l1);               \
            bh0 = short8{h0[0],h0[1],h0[2],h0[3],h1[0],h1[1],h1[2],h1[3]};    \
            bl0 = short8{l0[0],l0[1],l0[2],l0[3],l1[0],l1[1],l1[2],l1[3]};    \
            split4(rb[P][2], h0, l0); split4(rb[P][3], h1, l1);               \
            bh1 = short8{h0[0],h0[1],h0[2],h0[3],h1[0],h1[1],h1[2],h1[3]};    \
            bl1 = short8{l0[0],l0[1],l0[2],l0[3],l1[0],l1[1],l1[2],l1[3]};    \
        }                                                                     \
        if (DOL) LOADB(P, (K) + 3)                                            \
        __builtin_amdgcn_s_setprio(1);                                        \
        acc0 = MFMA32(aH0[P][0], bh0, acc0);                                  \
        acc1 = MFMA32(aH1[P][0], bh0, acc1);                                  \
        acc0 = MFMA32(aL0[P][0], bh0, acc0);                                  \
        acc1 = MFMA32(aL1[P][0], bh0, acc1);                                  \
        acc0 = MFMA32(aH0[P][0], bl0, acc0);                                  \
        acc1 = MFMA32(aH1[P][0], bl0, acc1);                                  \
        acc0 = MFMA32(aH0[P][1], bh1, acc0);                                  \
        acc1 = MFMA32(aH1[P][1], bh1, acc1);                                  \
        acc0 = MFMA32(aL0[P][1], bh1, acc0);                                  \
        acc1 = MFMA32(aL1[P][1], bh1, acc1);                                  \
        acc0 = MFMA32(aH0[P][1], bl1, acc0);                                  \
        acc1 = MFMA32(aH1[P][1], bl1, acc1);                                  \
        __builtin_amdgcn_s_setprio(0);                                        \
        if (DOL) LOADA(P, (K) + 3)                                            \
    }

    for (int k = 0; k < 27; k += 3) {
        BODY(0, k, 1)
        BODY(1, k + 1, 1)
        BODY(2, k + 2, 1)
    }
    BODY(0, 27, 1)      // loads slab 30 into set 0
    BODY(1, 28, 1)      // loads slab 31 into set 1
    BODY(2, 29, 0)
    BODY(0, 30, 0)
    BODY(1, 31, 0)
#undef BODY
#undef LOADA
#undef LOADB

    // 32x32 C/D layout: col = lane&31, row = (r&3) + 8*(r>>2) + 4*(lane>>5).
    const int col  = n0 + l31;
    const float bias = attn_b[col];
    const int rbase = s0 * 32 + (lane >> 5) * 4;
    float* dcol = hp + col;
    #pragma unroll
    for (int r = 0; r < 16; ++r) {
        const int row = rbase + (r & 3) + 8 * (r >> 2);
        dcol[(size_t)row * N1_]        = tanh_c(acc0[r] + bias);
        dcol[(size_t)(row + 32) * N1_] = tanh_c(acc1[r] + bias);
    }
}

// ---------------------------------------------------------------------------
// Kernel 2: tB[c,g,o] = tanh( sum_d enc[c,g,d] * attn_w[c,o,H+d] )
// Per-c GEMM M=32, N=1024, K=256; grid (16,16)=256 blocks.
// Prepass folded in: pack hidden (B,H) into bf16 hi/lo planes in MFMA-
// FRAGMENT order for gemm1's register-direct A loads:
//   hidP[s][k0][ks][lane][j] = hid[s*32+(lane&31)][k0*32+ks*16+(lane>>5)*8+j]
// (s=m-strip of 32 rows, k0=K-slab of 32, ks=k-half, j=0..7).
// ---------------------------------------------------------------------------
__global__ __launch_bounds__(256) void gemm2_kernel(
    const float* __restrict__ enc, const float* __restrict__ attn_w,
    const float* __restrict__ hidden, float* __restrict__ ep,
    short* __restrict__ hidH, short* __restrict__ hidL)
{
    const int tid  = threadIdx.x;
    const int wave = tid >> 6, lane = tid & 63;

    {   // fragment-pack prepass: 32768 lane-tasks over the first 128 blocks
        const int bid = blockIdx.y * 16 + blockIdx.x;
        const int gid = bid * 256 + tid;
        if (gid < 32768) {
            const int s   = gid >> 12;
            const int k0  = (gid >> 7) & 31;
            const int ks  = (gid >> 6) & 1;
            const int ln  = gid & 63;
            const int row = s * 32 + (ln & 31);
            const int colk = k0 * 32 + ks * 16 + (ln >> 5) * 8;
            const float* src = hidden + (size_t)row * H_ + colk;
            s16x4 h0, l0, h1, l1;
            split4(*(const float4*)src, h0, l0);
            split4(*(const float4*)(src + 4), h1, l1);
            *(short8*)(hidH + (size_t)gid * 8) =
                short8{h0[0],h0[1],h0[2],h0[3],h1[0],h1[1],h1[2],h1[3]};
            *(short8*)(hidL + (size_t)gid * 8) =
                short8{l0[0],l0[1],l0[2],l0[3],l1[0],l1[1],l1[2],l1[3]};
        }
    }

    const int c  = blockIdx.y;
    const int n0 = blockIdx.x * 64 + wave * 16;   // o tile, 16 per wave
    const int l16 = lane & 15;
    const int lk  = (lane >> 4) * 8;

#define MFMA16(a, b, c) __builtin_amdgcn_mfma_f32_16x16x32_bf16((a), (b), (c), 0, 0, 0)
    f32x4 acc[2];
    acc[0] = f32x4{0.f, 0.f, 0.f, 0.f};
    acc[1] = f32x4{0.f, 0.f, 0.f, 0.f};

    const float* encp = enc + c * (G_ * D_);
    const float* wp   = attn_w + (size_t)c * H_ * HD_ + H_;

    #pragma unroll
    for (int kk = 0; kk < 8; ++kk) {
        const int k0 = kk * 32 + lk;
        short8 ah[2], al[2], bh, bl;
        #pragma unroll
        for (int mi = 0; mi < 2; ++mi) {
            const float* p = encp + (mi * 16 + l16) * D_ + k0;
            s16x4 h0, l0, h1, l1;
            split4(*(const float4*)p, h0, l0);
            split4(*(const float4*)(p + 4), h1, l1);
            ah[mi] = short8{h0[0],h0[1],h0[2],h0[3],h1[0],h1[1],h1[2],h1[3]};
            al[mi] = short8{l0[0],l0[1],l0[2],l0[3],l1[0],l1[1],l1[2],l1[3]};
        }
        {
            const float* p = wp + (size_t)(n0 + l16) * HD_ + k0;
            s16x4 h0, l0, h1, l1;
            split4(*(const float4*)p, h0, l0);
            split4(*(const float4*)(p + 4), h1, l1);
            bh = short8{h0[0],h0[1],h0[2],h0[3],h1[0],h1[1],h1[2],h1[3]};
            bl = short8{l0[0],l0[1],l0[2],l0[3],l1[0],l1[1],l1[2],l1[3]};
        }
        #pragma unroll
        for (int mi = 0; mi < 2; ++mi) {
            acc[mi] = MFMA16(ah[mi], bh, acc[mi]);
            acc[mi] = MFMA16(al[mi], bh, acc[mi]);
            acc[mi] = MFMA16(ah[mi], bl, acc[mi]);
        }
    }

    const int lr = (lane >> 4) * 4;
    #pragma unroll
    for (int mi = 0; mi < 2; ++mi) {
        const int g = mi * 16 + lr;
        const int o = n0 + l16;
        float* dst = ep + (c * G_ + g) * H_ + o;
        f32x4 vacc = acc[mi];
        dst[0]      = tanh_c(vacc[0]);
        dst[H_]     = tanh_c(vacc[1]);
        dst[2 * H_] = tanh_c(vacc[2]);
        dst[3 * H_] = tanh_c(vacc[3]);
    }
#undef MFMA16
}

// ---------------------------------------------------------------------------
// Kernel 3: per (c, 4 b's): scores[g] = sum_h blend(tA,tB)*v where
// blend = (tA+tB)/(1+tA*tB) = tanh(A+B) exactly; softmax over g; att_cat out;
// weighted[b,c,d] = sum_g att*enc.
// ---------------------------------------------------------------------------
__global__ __launch_bounds__(256) void attn_kernel(
    const float* __restrict__ hp, const float* __restrict__ ep,
    const float* __restrict__ v, const float* __restrict__ enc,
    float* __restrict__ out, float* __restrict__ wt)
{
    const int c  = blockIdx.x;
    const int b0 = blockIdx.y * 4;
    const int tid  = threadIdx.x;
    const int wave = tid >> 6, lane = tid & 63;

    __shared__ float s_att[4][G_];
    __shared__ float s_sc[4][G_];

    // h index mapping: h = lane*4 + j*256 + e  (same partition for hp/ep/v)
    f32x4 vv[4], tav[4][4];
    const float* vrow = v + c * H_;
    #pragma unroll
    for (int j = 0; j < 4; ++j)
        vv[j] = *(const f32x4*)(vrow + lane * 4 + j * 256);
    #pragma unroll
    for (int bi = 0; bi < 4; ++bi) {
        const float* hprow = hp + (size_t)(b0 + bi) * N1_ + c * H_;
        #pragma unroll
        for (int j = 0; j < 4; ++j)
            tav[bi][j] = *(const f32x4*)(hprow + lane * 4 + j * 256);
    }

    #pragma unroll
    for (int gg = 0; gg < 8; ++gg) {
        const int g = wave * 8 + gg;
        const float* eprow = ep + (size_t)(c * G_ + g) * H_;
        float s[4] = {0.f, 0.f, 0.f, 0.f};
        #pragma unroll
        for (int j = 0; j < 4; ++j) {
            const f32x4 tb = *(const f32x4*)(eprow + lane * 4 + j * 256);
            #pragma unroll
            for (int e = 0; e < 4; ++e) {
                const float tbx = tb[e];
                const float w   = vv[j][e];
                #pragma unroll
                for (int bi = 0; bi < 4; ++bi) {
                    const float ta  = tav[bi][j][e];
                    const float num = ta + tbx;
                    const float den = fmaf(ta, tbx, 1.f);
                    s[bi] = fmaf(num * __builtin_amdgcn_rcpf(den), w, s[bi]);
                }
            }
        }
        #pragma unroll
        for (int off = 32; off > 0; off >>= 1) {
            s[0] += __shfl_down(s[0], off, 64);
            s[1] += __shfl_down(s[1], off, 64);
            s[2] += __shfl_down(s[2], off, 64);
            s[3] += __shfl_down(s[3], off, 64);
        }
        if (lane == 0) {
            s_sc[0][g] = s[0]; s_sc[1][g] = s[1];
            s_sc[2][g] = s[2]; s_sc[3][g] = s[3];
        }
    }
    __syncthreads();

    if (tid < 128) {
        const int bi = tid >> 5, g = tid & 31;
        float sv = s_sc[bi][g];
        float m = sv;
        #pragma unroll
        for (int off = 16; off > 0; off >>= 1)
            m = fmaxf(m, __shfl_xor(m, off, 32));
        const float e = __expf(sv - m);
        float sum = e;
        #pragma unroll
        for (int off = 16; off > 0; off >>= 1)
            sum += __shfl_xor(sum, off, 32);
        const float a = e / sum;
        s_att[bi][g] = a;
        out[(size_t)(b0 + bi) * (C_ * G_) + c * G_ + g] = a;   // att_cat
    }
    __syncthreads();

    // weighted[b,c,d], thread = d; enc element shared across the 4 b's
    float w0 = 0.f, w1 = 0.f, w2 = 0.f, w3 = 0.f;
    const float* encc = enc + c * (G_ * D_) + tid;
    #pragma unroll
    for (int g = 0; g < G_; ++g) {
        const float e = encc[g * D_];
        w0 = fmaf(s_att[0][g], e, w0);
        w1 = fmaf(s_att[1][g], e, w1);
        w2 = fmaf(s_att[2][g], e, w2);
        w3 = fmaf(s_att[3][g], e, w3);
    }
    wt[(size_t)((b0 + 0) * C_ + c) * D_ + tid] = w0;
    wt[(size_t)((b0 + 1) * C_ + c) * D_ + tid] = w1;
    wt[(size_t)((b0 + 2) * C_ + c) * D_ + tid] = w2;
    wt[(size_t)((b0 + 3) * C_ + c) * D_ + tid] = w3;
}

// ---------------------------------------------------------------------------
// Kernel 4: pooled[b,d] = mean_c weighted; out[b,o] = pooled.out_w[o,:] + out_b
// ---------------------------------------------------------------------------
__global__ __launch_bounds__(256) void out_kernel(
    const float* __restrict__ wt, const float* __restrict__ out_w,
    const float* __restrict__ out_b, float* __restrict__ out)
{
    const int b = blockIdx.x, tid = threadIdx.x;
    __shared__ float pooled[D_];

    float s = 0.f;
    #pragma unroll
    for (int c = 0; c < C_; ++c)
        s += wt[(size_t)(b * C_ + c) * D_ + tid];
    pooled[tid] = s * (1.f / 16.f);
    __syncthreads();

    float acc = out_b[tid];
    const float* wrow = out_w + tid * D_;
    #pragma unroll 8
    for (int dc = 0; dc < 64; ++dc) {
        float4 w4 = *(const float4*)(wrow + dc * 4);
        acc += pooled[dc * 4 + 0] * w4.x;
        acc += pooled[dc * 4 + 1] * w4.y;
        acc += pooled[dc * 4 + 2] * w4.z;
        acc += pooled[dc * 4 + 3] * w4.w;
    }
    out[(size_t)B_ * (C_ * G_) + b * O_ + tid] = acc;
}

extern "C" void kernel_launch(void* const* d_in, const int* in_sizes, int n_in,
                              void* d_out, int out_size, void* d_ws, size_t ws_size,
                              hipStream_t stream) {
    const float* hidden = (const float*)d_in[0];   // (B,H)     fp32
    const float* enc    = (const float*)d_in[1];   // (C,G,D)   fp32
    const float* attn_w = (const float*)d_in[2];   // (C,H,H+D) fp32
    const float* attn_b = (const float*)d_in[3];   // (C,H)     fp32
    const float* v      = (const float*)d_in[4];   // (C,H)     fp32
    const float* out_w  = (const float*)d_in[5];   // (O,D)     fp32
    const float* out_b  = (const float*)d_in[6];   // (O,)      fp32
    float* out = (float*)d_out;                    // att_cat (B,C*G) ++ out (B,O)

    float* hp = (float*)d_ws;                      // (B, C*H)  tA fp32: 16.78 MB
    float* ep = hp + (size_t)B_ * N1_;             // (C, G, H) tB fp32:  2.10 MB
    float* wt = ep + (size_t)C_ * G_ * H_;         // (B, C, D) fp32:     4.19 MB
    short* hidH = (short*)(wt + (size_t)B_ * C_ * D_);  // (B,H) bf16 hi frag-packed: 512 KB
    short* hidL = hidH + (size_t)B_ * H_;               // (B,H) bf16 lo frag-packed: 512 KB

    // gemm2 first: it also produces the fragment-packed hidden planes gemm1 reads.
    gemm2_kernel<<<dim3(16, C_), 256, 0, stream>>>(enc, attn_w, hidden, ep, hidH, hidL);
    gemm1_kernel<<<dim3(2, 256), 256, 0, stream>>>(hidH, hidL, attn_w, attn_b, hp);
    attn_kernel<<<dim3(C_, B_ / 4), 256, 0, stream>>>(hp, ep, v, enc, out, wt);
    out_kernel<<<B_, 256, 0, stream>>>(wt, out_w, out_b, out);
}

// Round 6
// 210.606 us; speedup vs baseline: 1.0925x; 1.0925x over previous
//
#include <hip/hip_runtime.h>
#include <hip/hip_bf16.h>

#define B_  256
#define H_  1024
#define D_  256
#define G_  32
#define C_  16
#define O_  256
#define HD_ 1280          // H + D
#define N1_ 16384         // C*H

typedef __attribute__((ext_vector_type(8)))  short short8;
typedef __attribute__((ext_vector_type(4)))  short s16x4;
typedef __attribute__((ext_vector_type(4)))  float f32x4;
typedef __attribute__((ext_vector_type(16))) float f32x16;

#define MFMA32(a, b, c) __builtin_amdgcn_mfma_f32_32x32x16_bf16((a), (b), (c), 0, 0, 0)

// tanh via fast exp + hw rcp; clamped to +-(1-6e-8) so that the downstream
// blend denominator 1 + tA*tB is always > 0 (never 0*inf = NaN).
__device__ __forceinline__ float tanh_c(float x) {
    float y = __expf(2.f * x);
    float t = 1.f - 2.f * __builtin_amdgcn_rcpf(y + 1.f);
    return fminf(fmaxf(t, -0.99999994f), 0.99999994f);
}

// Split fp32 into bf16 hi + bf16 lo (both truncated).
__device__ __forceinline__ short bfhi(float x) {
    return (short)(__float_as_uint(x) >> 16);
}
__device__ __forceinline__ short bflo(float x) {
    float fhi = __uint_as_float(__float_as_uint(x) & 0xFFFF0000u);
    return (short)(__float_as_uint(x - fhi) >> 16);
}

__device__ __forceinline__ void split4(const float4 v, s16x4& hi, s16x4& lo) {
    hi[0] = bfhi(v.x); lo[0] = bflo(v.x);
    hi[1] = bfhi(v.y); lo[1] = bflo(v.y);
    hi[2] = bfhi(v.z); lo[2] = bflo(v.z);
    hi[3] = bfhi(v.w); lo[3] = bflo(v.w);
}

// ---------------------------------------------------------------------------
// Kernel 1: tA[b, c*H+o] = tanh( sum_h hidden[b,h]*attn_w[c,o,h] + attn_b[c,o] )
// GEMM M=256, N=16384, K=1024.  BM=256 x BN=32, BK=32, grid 512, 4 waves,
// wave = 64m x 32n (2x 32x32x16 accs).  Round-6 = round-4 geometry with the
// HBM-latency defect fixed:
//   - B staged via global_load_lds (1 dwordx4 DMA / thread / slab) into a
//     4-buffer LDS ring, issued 3 SLABS AHEAD (~1500cy cover > ~900cy HBM
//     latency).  No VGPR round trip, no ds_write, no lgkmcnt(0) in the chain.
//   - counted s_waitcnt vmcnt(N) per iter (steady N=18, never 0): in-flight
//     DMAs and A-prefetch loads cross the barrier.  Issue order pinned with
//     sched_barrier(0) so the counts are exact: [A(k+1) x8][DMA(k+3)].
//   - B is fp32 in LDS with XOR-chunk swizzle (source-permuted; the read
//     applies the same involution) -> conflict-free width-floor ds_reads;
//     bf16 hi/lo split happens on read (overlaps other wave's MFMA).
//   - A: prepacked bf16 hi/lo fragments (gemm2 prepass), L2-resident, loaded
//     1 slab ahead into parity register sets.
// ---------------------------------------------------------------------------
__global__ __launch_bounds__(256, 2) void gemm1_kernel(
    const short* __restrict__ hidH, const short* __restrict__ hidL,
    const float* __restrict__ attn_w, const float* __restrict__ attn_b,
    float* __restrict__ hp)
{
    __shared__ float Bsf[4][32 * 32];     // 4-deep DMA ring, 4 KB/slab

    const int tid  = threadIdx.x;
    const int wave = tid >> 6, lane = tid & 63;
    const int l31  = lane & 31;
    const int hi2  = (lane >> 5) * 2;     // k-half chunk base (16B chunks)
    const int sw   = l31 & 7;             // read-side XOR swizzle
    const int n0   = blockIdx.x * 32;

    f32x16 acc0, acc1;
    #pragma unroll
    for (int i = 0; i < 16; ++i) { acc0[i] = 0.f; acc1[i] = 0.f; }

    // DMA source: thread stages 16B.  row r = tid>>3 (wave w owns rows
    // 8w..8w+7, matching the linear lane x 16B LDS landing), phys chunk
    // pc = tid&7 holds logical chunk pc ^ (r&7)  => source chunk is XORed.
    const int rS = tid >> 3;
    const int cS = (tid & 7) ^ (rS & 7);
    const float* pBsrc = attn_w + (size_t)(n0 + rS) * HD_ + cS * 4;

    // A fragment bases (hidP layout: [s][k0][ks][lane][8] shorts; wave owns
    // strips 2w, 2w+1 = rows w*64..w*64+63).
    const size_t aBase = (size_t)(wave * 2) * 32768 + (size_t)lane * 8;
    const short* pH0 = hidH + aBase;
    const short* pH1 = hidH + aBase + 32768;
    const short* pL0 = hidL + aBase;
    const short* pL1 = hidL + aBase + 32768;

    short8 aH0[2][2], aH1[2][2], aL0[2][2], aL1[2][2];   // [parity][ks]

#define LOADA(SET, K)                                                         \
    {                                                                         \
        const int o_ = (K) * 1024;                                            \
        aH0[SET][0] = *(const short8*)(pH0 + o_);                             \
        aH0[SET][1] = *(const short8*)(pH0 + o_ + 512);                       \
        aH1[SET][0] = *(const short8*)(pH1 + o_);                             \
        aH1[SET][1] = *(const short8*)(pH1 + o_ + 512);                       \
        aL0[SET][0] = *(const short8*)(pL0 + o_);                             \
        aL0[SET][1] = *(const short8*)(pL0 + o_ + 512);                       \
        aL1[SET][0] = *(const short8*)(pL1 + o_);                             \
        aL1[SET][1] = *(const short8*)(pL1 + o_ + 512);                       \
    }

#define DMAB(BUF, K)                                                          \
    __builtin_amdgcn_global_load_lds(                                         \
        (const __attribute__((address_space(1))) void*)(pBsrc + (K) * 32),    \
        (__attribute__((address_space(3))) void*)(&Bsf[BUF][wave * 256]),     \
        16, 0, 0);

    // Read logical chunk kc of row l31 at phys chunk kc ^ sw; split to hi/lo.
#define READB(BUF, KS, BH, BL)                                                \
    {                                                                         \
        const float* rp_ = &Bsf[BUF][l31 * 32];                               \
        const int kc_ = (KS) * 4 + hi2;                                       \
        float4 ca_ = *(const float4*)(rp_ + ((kc_    ) ^ sw) * 4);            \
        float4 cb_ = *(const float4*)(rp_ + ((kc_ + 1) ^ sw) * 4);            \
        s16x4 h0_, lo0_, h1_, lo1_;                                           \
        split4(ca_, h0_, lo0_);                                               \
        split4(cb_, h1_, lo1_);                                               \
        BH = short8{h0_[0],h0_[1],h0_[2],h0_[3],h1_[0],h1_[1],h1_[2],h1_[3]}; \
        BL = short8{lo0_[0],lo0_[1],lo0_[2],lo0_[3],                          \
                    lo1_[0],lo1_[1],lo1_[2],lo1_[3]};                         \
    }

    // Per-iter: wait DMA(K) (counted vmcnt -- newer in flight stay), barrier,
    // issue A(K+1), then DMA(K+3) (order pinned => exact counts), read+split
    // B(K) from ring buf K&3, 12 MFMA.  One barrier per slab.
#define ITER(P, K, VC, DOL, DODMA)                                            \
    {                                                                         \
        asm volatile("s_waitcnt vmcnt(" #VC ")" ::: "memory");                \
        __builtin_amdgcn_s_barrier();                                         \
        if (DOL) LOADA(P ^ 1, (K) + 1)                                        \
        __builtin_amdgcn_sched_barrier(0);                                    \
        if (DODMA) DMAB(((K) + 3) & 3, (K) + 3)                               \
        __builtin_amdgcn_sched_barrier(0);                                    \
        short8 bh0, bl0, bh1, bl1;                                            \
        READB((K) & 3, 0, bh0, bl0)                                           \
        READB((K) & 3, 1, bh1, bl1)                                           \
        __builtin_amdgcn_s_setprio(1);                                        \
        acc0 = MFMA32(aH0[P][0], bh0, acc0);                                  \
        acc1 = MFMA32(aH1[P][0], bh0, acc1);                                  \
        acc0 = MFMA32(aL0[P][0], bh0, acc0);                                  \
        acc1 = MFMA32(aL1[P][0], bh0, acc1);                                  \
        acc0 = MFMA32(aH0[P][0], bl0, acc0);                                  \
        acc1 = MFMA32(aH1[P][0], bl0, acc1);                                  \
        acc0 = MFMA32(aH0[P][1], bh1, acc0);                                  \
        acc1 = MFMA32(aH1[P][1], bh1, acc1);                                  \
        acc0 = MFMA32(aL0[P][1], bh1, acc0);                                  \
        acc1 = MFMA32(aL1[P][1], bh1, acc1);                                  \
        acc0 = MFMA32(aH0[P][1], bl1, acc0);                                  \
        acc1 = MFMA32(aH1[P][1], bl1, acc1);                                  \
        __builtin_amdgcn_s_setprio(0);                                        \
    }

    // Prologue: DMA slabs 0,1,2 into ring 0,1,2; A slab 0 into set 0.
    DMAB(0, 0)
    DMAB(1, 1)
    DMAB(2, 2)
    __builtin_amdgcn_sched_barrier(0);
    LOADA(0, 0)

    // vmcnt counts (exact, from pinned issue order; DMA ring depth 3):
    //   k=0:10  k=1:18  k=2:26  k=3..28:18  k=29:18  k=30:17  k=31:16
    ITER(0, 0, 10, 1, 1)
    ITER(1, 1, 18, 1, 1)
    ITER(0, 2, 26, 1, 1)
    for (int k = 3; k <= 27; k += 2) {
        ITER(1, k,     18, 1, 1)
        ITER(0, k + 1, 18, 1, 1)
    }
    ITER(1, 29, 18, 1, 0)
    ITER(0, 30, 17, 1, 0)
    ITER(1, 31, 16, 0, 0)
#undef ITER
#undef READB
#undef DMAB
#undef LOADA

    // 32x32 C/D layout: col = lane&31, row = (r&3) + 8*(r>>2) + 4*(lane>>5).
    const int col  = n0 + l31;
    const float bias = attn_b[col];
    const int rbase = wave * 64 + (lane >> 5) * 4;
    float* dcol = hp + col;
    #pragma unroll
    for (int r = 0; r < 16; ++r) {
        const int row = rbase + (r & 3) + 8 * (r >> 2);
        dcol[(size_t)row * N1_]        = tanh_c(acc0[r] + bias);
        dcol[(size_t)(row + 32) * N1_] = tanh_c(acc1[r] + bias);
    }
}

// ---------------------------------------------------------------------------
// Kernel 2: tB[c,g,o] = tanh( sum_d enc[c,g,d] * attn_w[c,o,H+d] )
// Per-c GEMM M=32, N=1024, K=256; grid (16,16)=256 blocks.
// Prepass folded in: pack hidden (B,H) into bf16 hi/lo planes in MFMA-
// FRAGMENT order for gemm1's register-direct A loads:
//   hidP[s][k0][ks][lane][j] = hid[s*32+(lane&31)][k0*32+ks*16+(lane>>5)*8+j]
// ---------------------------------------------------------------------------
__global__ __launch_bounds__(256) void gemm2_kernel(
    const float* __restrict__ enc, const float* __restrict__ attn_w,
    const float* __restrict__ hidden, float* __restrict__ ep,
    short* __restrict__ hidH, short* __restrict__ hidL)
{
    const int tid  = threadIdx.x;
    const int wave = tid >> 6, lane = tid & 63;

    {   // fragment-pack prepass: 32768 lane-tasks over the first 128 blocks
        const int bid = blockIdx.y * 16 + blockIdx.x;
        const int gid = bid * 256 + tid;
        if (gid < 32768) {
            const int s   = gid >> 12;
            const int k0  = (gid >> 7) & 31;
            const int ks  = (gid >> 6) & 1;
            const int ln  = gid & 63;
            const int row = s * 32 + (ln & 31);
            const int colk = k0 * 32 + ks * 16 + (ln >> 5) * 8;
            const float* src = hidden + (size_t)row * H_ + colk;
            s16x4 h0, l0, h1, l1;
            split4(*(const float4*)src, h0, l0);
            split4(*(const float4*)(src + 4), h1, l1);
            *(short8*)(hidH + (size_t)gid * 8) =
                short8{h0[0],h0[1],h0[2],h0[3],h1[0],h1[1],h1[2],h1[3]};
            *(short8*)(hidL + (size_t)gid * 8) =
                short8{l0[0],l0[1],l0[2],l0[3],l1[0],l1[1],l1[2],l1[3]};
        }
    }

    const int c  = blockIdx.y;
    const int n0 = blockIdx.x * 64 + wave * 16;   // o tile, 16 per wave
    const int l16 = lane & 15;
    const int lk  = (lane >> 4) * 8;

#define MFMA16(a, b, c) __builtin_amdgcn_mfma_f32_16x16x32_bf16((a), (b), (c), 0, 0, 0)
    f32x4 acc[2];
    acc[0] = f32x4{0.f, 0.f, 0.f, 0.f};
    acc[1] = f32x4{0.f, 0.f, 0.f, 0.f};

    const float* encp = enc + c * (G_ * D_);
    const float* wp   = attn_w + (size_t)c * H_ * HD_ + H_;

    #pragma unroll
    for (int kk = 0; kk < 8; ++kk) {
        const int k0 = kk * 32 + lk;
        short8 ah[2], al[2], bh, bl;
        #pragma unroll
        for (int mi = 0; mi < 2; ++mi) {
            const float* p = encp + (mi * 16 + l16) * D_ + k0;
            s16x4 h0, l0, h1, l1;
            split4(*(const float4*)p, h0, l0);
            split4(*(const float4*)(p + 4), h1, l1);
            ah[mi] = short8{h0[0],h0[1],h0[2],h0[3],h1[0],h1[1],h1[2],h1[3]};
            al[mi] = short8{l0[0],l0[1],l0[2],l0[3],l1[0],l1[1],l1[2],l1[3]};
        }
        {
            const float* p = wp + (size_t)(n0 + l16) * HD_ + k0;
            s16x4 h0, l0, h1, l1;
            split4(*(const float4*)p, h0, l0);
            split4(*(const float4*)(p + 4), h1, l1);
            bh = short8{h0[0],h0[1],h0[2],h0[3],h1[0],h1[1],h1[2],h1[3]};
            bl = short8{l0[0],l0[1],l0[2],l0[3],l1[0],l1[1],l1[2],l1[3]};
        }
        #pragma unroll
        for (int mi = 0; mi < 2; ++mi) {
            acc[mi] = MFMA16(ah[mi], bh, acc[mi]);
            acc[mi] = MFMA16(al[mi], bh, acc[mi]);
            acc[mi] = MFMA16(ah[mi], bl, acc[mi]);
        }
    }

    const int lr = (lane >> 4) * 4;
    #pragma unroll
    for (int mi = 0; mi < 2; ++mi) {
        const int g = mi * 16 + lr;
        const int o = n0 + l16;
        float* dst = ep + (c * G_ + g) * H_ + o;
        f32x4 vacc = acc[mi];
        dst[0]      = tanh_c(vacc[0]);
        dst[H_]     = tanh_c(vacc[1]);
        dst[2 * H_] = tanh_c(vacc[2]);
        dst[3 * H_] = tanh_c(vacc[3]);
    }
#undef MFMA16
}

// ---------------------------------------------------------------------------
// Kernel 3: per (c, 4 b's): scores[g] = sum_h blend(tA,tB)*v where
// blend = (tA+tB)/(1+tA*tB) = tanh(A+B) exactly; softmax over g; att_cat out;
// weighted[b,c,d] = sum_g att*enc.
// ---------------------------------------------------------------------------
__global__ __launch_bounds__(256) void attn_kernel(
    const float* __restrict__ hp, const float* __restrict__ ep,
    const float* __restrict__ v, const float* __restrict__ enc,
    float* __restrict__ out, float* __restrict__ wt)
{
    const int c  = blockIdx.x;
    const int b0 = blockIdx.y * 4;
    const int tid  = threadIdx.x;
    const int wave = tid >> 6, lane = tid & 63;

    __shared__ float s_att[4][G_];
    __shared__ float s_sc[4][G_];

    // h index mapping: h = lane*4 + j*256 + e  (same partition for hp/ep/v)
    f32x4 vv[4], tav[4][4];
    const float* vrow = v + c * H_;
    #pragma unroll
    for (int j = 0; j < 4; ++j)
        vv[j] = *(const f32x4*)(vrow + lane * 4 + j * 256);
    #pragma unroll
    for (int bi = 0; bi < 4; ++bi) {
        const float* hprow = hp + (size_t)(b0 + bi) * N1_ + c * H_;
        #pragma unroll
        for (int j = 0; j < 4; ++j)
            tav[bi][j] = *(const f32x4*)(hprow + lane * 4 + j * 256);
    }

    #pragma unroll
    for (int gg = 0; gg < 8; ++gg) {
        const int g = wave * 8 + gg;
        const float* eprow = ep + (size_t)(c * G_ + g) * H_;
        float s[4] = {0.f, 0.f, 0.f, 0.f};
        #pragma unroll
        for (int j = 0; j < 4; ++j) {
            const f32x4 tb = *(const f32x4*)(eprow + lane * 4 + j * 256);
            #pragma unroll
            for (int e = 0; e < 4; ++e) {
                const float tbx = tb[e];
                const float w   = vv[j][e];
                #pragma unroll
                for (int bi = 0; bi < 4; ++bi) {
                    const float ta  = tav[bi][j][e];
                    const float num = ta + tbx;
                    const float den = fmaf(ta, tbx, 1.f);
                    s[bi] = fmaf(num * __builtin_amdgcn_rcpf(den), w, s[bi]);
                }
            }
        }
        #pragma unroll
        for (int off = 32; off > 0; off >>= 1) {
            s[0] += __shfl_down(s[0], off, 64);
            s[1] += __shfl_down(s[1], off, 64);
            s[2] += __shfl_down(s[2], off, 64);
            s[3] += __shfl_down(s[3], off, 64);
        }
        if (lane == 0) {
            s_sc[0][g] = s[0]; s_sc[1][g] = s[1];
            s_sc[2][g] = s[2]; s_sc[3][g] = s[3];
        }
    }
    __syncthreads();

    if (tid < 128) {
        const int bi = tid >> 5, g = tid & 31;
        float sv = s_sc[bi][g];
        float m = sv;
        #pragma unroll
        for (int off = 16; off > 0; off >>= 1)
            m = fmaxf(m, __shfl_xor(m, off, 32));
        const float e = __expf(sv - m);
        float sum = e;
        #pragma unroll
        for (int off = 16; off > 0; off >>= 1)
            sum += __shfl_xor(sum, off, 32);
        const float a = e / sum;
        s_att[bi][g] = a;
        out[(size_t)(b0 + bi) * (C_ * G_) + c * G_ + g] = a;   // att_cat
    }
    __syncthreads();

    // weighted[b,c,d], thread = d; enc element shared across the 4 b's
    float w0 = 0.f, w1 = 0.f, w2 = 0.f, w3 = 0.f;
    const float* encc = enc + c * (G_ * D_) + tid;
    #pragma unroll
    for (int g = 0; g < G_; ++g) {
        const float e = encc[g * D_];
        w0 = fmaf(s_att[0][g], e, w0);
        w1 = fmaf(s_att[1][g], e, w1);
        w2 = fmaf(s_att[2][g], e, w2);
        w3 = fmaf(s_att[3][g], e, w3);
    }
    wt[(size_t)((b0 + 0) * C_ + c) * D_ + tid] = w0;
    wt[(size_t)((b0 + 1) * C_ + c) * D_ + tid] = w1;
    wt[(size_t)((b0 + 2) * C_ + c) * D_ + tid] = w2;
    wt[(size_t)((b0 + 3) * C_ + c) * D_ + tid] = w3;
}

// ---------------------------------------------------------------------------
// Kernel 4: pooled[b,d] = mean_c weighted; out[b,o] = pooled.out_w[o,:] + out_b
// ---------------------------------------------------------------------------
__global__ __launch_bounds__(256) void out_kernel(
    const float* __restrict__ wt, const float* __restrict__ out_w,
    const float* __restrict__ out_b, float* __restrict__ out)
{
    const int b = blockIdx.x, tid = threadIdx.x;
    __shared__ float pooled[D_];

    float s = 0.f;
    #pragma unroll
    for (int c = 0; c < C_; ++c)
        s += wt[(size_t)(b * C_ + c) * D_ + tid];
    pooled[tid] = s * (1.f / 16.f);
    __syncthreads();

    float acc = out_b[tid];
    const float* wrow = out_w + tid * D_;
    #pragma unroll 8
    for (int dc = 0; dc < 64; ++dc) {
        float4 w4 = *(const float4*)(wrow + dc * 4);
        acc += pooled[dc * 4 + 0] * w4.x;
        acc += pooled[dc * 4 + 1] * w4.y;
        acc += pooled[dc * 4 + 2] * w4.z;
        acc += pooled[dc * 4 + 3] * w4.w;
    }
    out[(size_t)B_ * (C_ * G_) + b * O_ + tid] = acc;
}

extern "C" void kernel_launch(void* const* d_in, const int* in_sizes, int n_in,
                              void* d_out, int out_size, void* d_ws, size_t ws_size,
                              hipStream_t stream) {
    const float* hidden = (const float*)d_in[0];   // (B,H)     fp32
    const float* enc    = (const float*)d_in[1];   // (C,G,D)   fp32
    const float* attn_w = (const float*)d_in[2];   // (C,H,H+D) fp32
    const float* attn_b = (const float*)d_in[3];   // (C,H)     fp32
    const float* v      = (const float*)d_in[4];   // (C,H)     fp32
    const float* out_w  = (const float*)d_in[5];   // (O,D)     fp32
    const float* out_b  = (const float*)d_in[6];   // (O,)      fp32
    float* out = (float*)d_out;                    // att_cat (B,C*G) ++ out (B,O)

    float* hp = (float*)d_ws;                      // (B, C*H)  tA fp32: 16.78 MB
    float* ep = hp + (size_t)B_ * N1_;             // (C, G, H) tB fp32:  2.10 MB
    float* wt = ep + (size_t)C_ * G_ * H_;         // (B, C, D) fp32:     4.19 MB
    short* hidH = (short*)(wt + (size_t)B_ * C_ * D_);  // (B,H) bf16 hi frag-packed: 512 KB
    short* hidL = hidH + (size_t)B_ * H_;               // (B,H) bf16 lo frag-packed: 512 KB

    // gemm2 first: it also produces the fragment-packed hidden planes gemm1 reads.
    gemm2_kernel<<<dim3(16, C_), 256, 0, stream>>>(enc, attn_w, hidden, ep, hidH, hidL);
    gemm1_kernel<<<512, 256, 0, stream>>>(hidH, hidL, attn_w, attn_b, hp);
    attn_kernel<<<dim3(C_, B_ / 4), 256, 0, stream>>>(hp, ep, v, enc, out, wt);
    out_kernel<<<B_, 256, 0, stream>>>(wt, out_w, out_b, out);
}